// Round 14
// baseline (249.497 us; speedup 1.0000x reference)
//
#include <hip/hip_runtime.h>
#include <stdint.h>

#define Bb 8
#define Tt 1024
#define Cc 512
#define Hh 8
#define HD 64
#define MREL 68
#define NR 137           // 2*MREL+1
#define NRP 160          // k-extent padded for MFMA windows
#define SCALE 0.044194173824159216f     // 1/sqrt(512)  (ref scales by embed dim!)
#define KSCL  0.063763016845703125f     // SCALE * log2(e)

typedef unsigned short u16;
typedef unsigned int u32;
using u16x4  = __attribute__((ext_vector_type(4))) u16;
using u16x8  = __attribute__((ext_vector_type(8))) u16;
using u32x4  = __attribute__((ext_vector_type(4))) u32;
using f32x4  = __attribute__((ext_vector_type(4))) float;
using f32x16 = __attribute__((ext_vector_type(16))) float;
using bf16x8 = __attribute__((ext_vector_type(8))) __bf16;

__device__ __forceinline__ u16 f2bf(float f) {
  u32 u = __builtin_bit_cast(u32, f);
  u += 0x7FFF + ((u >> 16) & 1);       // RTNE
  return (u16)(u >> 16);
}
__device__ __forceinline__ float bf2f(u16 v) {
  return __builtin_bit_cast(float, (u32)v << 16);
}
__device__ __forceinline__ bf16x8 as_bf8(u16x8 v) { return __builtin_bit_cast(bf16x8, v); }
__device__ __forceinline__ bf16x8 frag4(u32 w0, u32 w1, u32 w2, u32 w3) {
  u32x4 v = {w0, w1, w2, w3};
  return __builtin_bit_cast(bf16x8, v);
}
__device__ __forceinline__ float fexp2(float x) {
  float r; asm("v_exp_f32 %0, %1" : "=v"(r) : "v"(x)); return r;
}
__device__ __forceinline__ u32 cvtpk(float lo, float hi) {
  u32 r; asm("v_cvt_pk_bf16_f32 %0, %1, %2" : "=v"(r) : "v"(lo), "v"(hi)); return r;
}
// split-placement load: words 0-1 <- base[0..3], words 2-3 <- base[8..11].
// Placement function matches the QK^T C/D row interleave, so P-fragments
// (assembled in-register) and V-fragments (loaded) pair correctly for ANY
// true HW k-layout (bijection cancels inside the MFMA dot product).
__device__ __forceinline__ bf16x8 ldsplit(const u16* base) {
  u16x4 lo = *(const u16x4*)(base);
  u16x4 hi = *(const u16x4*)(base + 8);
  u16x8 r = {lo[0], lo[1], lo[2], lo[3], hi[0], hi[1], hi[2], hi[3]};
  return as_bf8(r);
}

#define MFMA16(a, b, c) __builtin_amdgcn_mfma_f32_16x16x32_bf16((a), (b), (c), 0, 0, 0)
#define MFMA32(a, b, c) __builtin_amdgcn_mfma_f32_32x32x16_bf16((a), (b), (c), 0, 0, 0)

// ---------------------------------------------------------------------------
// Kernel 0a: transpose rel_v to bf16 [d][r] with zero pad.
// ---------------------------------------------------------------------------
__global__ __launch_bounds__(256) void relv_prep(
    const float* __restrict__ rel_v, u16* __restrict__ rvT)
{
  int i = blockIdx.x * 256 + threadIdx.x;
  if (i < HD * NRP) {
    int d = i / NRP, r = i - d * NRP;
    rvT[i] = (r < NR) ? f2bf(rel_v[r * HD + d]) : (u16)0;
  }
}

// ---------------------------------------------------------------------------
// Kernel 0b: convert the four 512x512 weights to bf16, TRANSPOSED [n][k].
// ---------------------------------------------------------------------------
__global__ __launch_bounds__(256) void w_prep(
    const float* __restrict__ Wq, const float* __restrict__ Wk,
    const float* __restrict__ Wv, const float* __restrict__ Wo,
    u16* __restrict__ WqT, u16* __restrict__ WkT,
    u16* __restrict__ WvT, u16* __restrict__ WoT)
{
  const float* W = blockIdx.y == 0 ? Wq : blockIdx.y == 1 ? Wk
                  : blockIdx.y == 2 ? Wv : Wo;
  u16* WT = blockIdx.y == 0 ? WqT : blockIdx.y == 1 ? WkT
           : blockIdx.y == 2 ? WvT : WoT;
  int i = blockIdx.x * 256 + threadIdx.x;   // over 512*128
  int n = i >> 7, k4 = (i & 127) * 4;
  u16x4 o;
  #pragma unroll
  for (int j = 0; j < 4; ++j) o[j] = f2bf(W[(size_t)(k4 + j) * Cc + n]);
  *(u16x4*)&WT[(size_t)n * Cc + k4] = o;
}

// ---------------------------------------------------------------------------
// Kernel 1: fused QKV projection (unchanged).
// ---------------------------------------------------------------------------
__global__ __launch_bounds__(256) void qkv_gemm(
    const float* __restrict__ x,
    const u16* __restrict__ WqT, const u16* __restrict__ WkT,
    const u16* __restrict__ WvT,
    const float* __restrict__ bq, const float* __restrict__ bk,
    const float* __restrict__ bv,
    u16* __restrict__ Qb, u16* __restrict__ Kb, u16* __restrict__ VTb)
{
  __shared__ u16 Xs[64][40];
  __shared__ u16 WTs[3][64][40];

  const u16* Wp[3] = {WqT, WkT, WvT};
  const float* bp[3] = {bq, bk, bv};

  const int tid = threadIdx.x;
  const int wv_ = tid >> 6;
  const int l   = tid & 63;
  const int lr  = l & 15, lg = l >> 4;
  const int m0  = blockIdx.x * 64;
  const int n0  = blockIdx.y * 64;
  const int srow = tid >> 2, scol = (tid & 3) * 8;

  f32x4 acc[3][4];
  #pragma unroll
  for (int a = 0; a < 3; ++a)
    #pragma unroll
    for (int b = 0; b < 4; ++b) acc[a][b] = (f32x4){0.f, 0.f, 0.f, 0.f};

  for (int k0 = 0; k0 < Cc; k0 += 32) {
    {
      const float* xp = x + (size_t)(m0 + srow) * Cc + k0 + scol;
      f32x4 v0 = *(const f32x4*)xp;
      f32x4 v1 = *(const f32x4*)(xp + 4);
      u16x8 o = {f2bf(v0[0]), f2bf(v0[1]), f2bf(v0[2]), f2bf(v0[3]),
                 f2bf(v1[0]), f2bf(v1[1]), f2bf(v1[2]), f2bf(v1[3])};
      *(u16x8*)&Xs[srow][scol] = o;
    }
    #pragma unroll
    for (int q3 = 0; q3 < 3; ++q3) {
      u16x8 w = *(const u16x8*)(Wp[q3] + (size_t)(n0 + srow) * Cc + k0 + scol);
      *(u16x8*)&WTs[q3][srow][scol] = w;
    }
    __syncthreads();

    bf16x8 a = as_bf8(*(const u16x8*)&Xs[wv_ * 16 + lr][lg * 8]);
    #pragma unroll
    for (int q3 = 0; q3 < 3; ++q3) {
      #pragma unroll
      for (int nt = 0; nt < 4; ++nt) {
        bf16x8 b = as_bf8(*(const u16x8*)&WTs[q3][nt * 16 + lr][lg * 8]);
        acc[q3][nt] = MFMA16(a, b, acc[q3][nt]);
      }
    }
    __syncthreads();
  }

  const int bidx = m0 >> 10;
  #pragma unroll
  for (int q3 = 0; q3 < 3; ++q3) {
    #pragma unroll
    for (int nt = 0; nt < 4; ++nt) {
      int n = n0 + nt * 16 + lr;
      int h = n >> 6, d = n & 63;
      float bias = bp[q3][n];
      #pragma unroll
      for (int i = 0; i < 4; ++i) {
        int m = m0 + wv_ * 16 + lg * 4 + i;
        int t = m & (Tt - 1);
        u16 o = f2bf(acc[q3][nt][i] + bias);
        size_t bh = (size_t)(bidx * Hh + h);
        if (q3 == 0)      Qb[(bh * Tt + t) * HD + d] = o;
        else if (q3 == 1) Kb[(bh * Tt + t) * HD + d] = o;
        else              VTb[(bh * HD + d) * Tt + t] = o;
      }
    }
  }
}

// ---------------------------------------------------------------------------
// Kernel 2: relative attention. Block = (b,h) x 32 q-rows; wave owns a
// 256-wide kc quarter. Swapped 32x32x16 QK^T -> lane holds P[q=lane&31][16kc]
// in registers; PV A-fragments built with cvt_pk ONLY (no cross-lane ops) —
// V loaded with the matching split placement (layout-proof by cancellation).
// Zero barriers in the k-loop.
// ---------------------------------------------------------------------------
__global__ __launch_bounds__(256, 3) void attn_kernel(
    const u16* __restrict__ Qb, const u16* __restrict__ Kb,
    const u16* __restrict__ VTb, const u16* __restrict__ rvT,
    const float* __restrict__ rel_k,
    u16* __restrict__ AO)
{
  __shared__ u16 S2L[32][144];     // (Q @ rel_k^T) * KSCL
  __shared__ u16 a2L[32][176];     // aggregated P over rel index (16B rows)
  __shared__ float Obuf[32][64];   // O accumulator across waves
  __shared__ float red[3][4][32];  // rowsum / s0 / band partials per wave
  __shared__ float rowrcp[32];

  const int tid = threadIdx.x;
  const int wv_ = tid >> 6, l = tid & 63;
  const int l31 = l & 31, hi = l >> 5;
  const int lr16 = l & 15, lg16 = l >> 4;
  const int bh = blockIdx.x;           // FAST dim -> XCD = bh % 8
  const int q0 = blockIdx.y * 32;
  const int bidx = bh >> 3, h = bh & 7;

  const u16* Qh = Qb  + (size_t)bh * Tt * HD;
  const u16* Kh = Kb  + (size_t)bh * Tt * HD;
  const u16* Vh = VTb + (size_t)bh * HD * Tt;

  // zero a2L + Obuf
  for (int i = tid; i < 32 * 176 / 2; i += 256) ((u32*)a2L)[i] = 0;
  for (int i = tid; i < 32 * 64; i += 256) ((float*)Obuf)[i] = 0.f;

  // ---- S2 = (Q @ rel_k^T) * KSCL  (16x16 MFMA, two q-halves) ----
  #pragma unroll
  for (int h16 = 0; h16 < 2; ++h16) {
    bf16x8 aQ0 = as_bf8(*(const u16x8*)(Qh + (size_t)(q0 + h16 * 16 + lr16) * HD + lg16 * 8));
    bf16x8 aQ1 = as_bf8(*(const u16x8*)(Qh + (size_t)(q0 + h16 * 16 + lr16) * HD + 32 + lg16 * 8));
    for (int ct = wv_; ct < 9; ct += 4) {
      int r = ct * 16 + lr16;
      f32x4 acc = {0.f, 0.f, 0.f, 0.f};
      #pragma unroll
      for (int d0 = 0; d0 < 64; d0 += 32) {
        u16x8 bbits = {0, 0, 0, 0, 0, 0, 0, 0};
        if (r < NR) {
          f32x4 v0 = *(const f32x4*)(rel_k + (size_t)r * HD + d0 + lg16 * 8);
          f32x4 v1 = *(const f32x4*)(rel_k + (size_t)r * HD + d0 + lg16 * 8 + 4);
          bbits = (u16x8){f2bf(v0[0]), f2bf(v0[1]), f2bf(v0[2]), f2bf(v0[3]),
                          f2bf(v1[0]), f2bf(v1[1]), f2bf(v1[2]), f2bf(v1[3])};
        }
        acc = MFMA16(d0 ? aQ1 : aQ0, as_bf8(bbits), acc);
      }
      #pragma unroll
      for (int i = 0; i < 4; ++i)
        S2L[h16 * 16 + lg16 * 4 + i][ct * 16 + lr16] = f2bf(acc[i] * KSCL);
    }
  }
  __syncthreads();

  // ---- per-lane setup (q = q0 + l31 is FIXED) ----
  const int qme = q0 + l31;
  const float cN = bf2f(S2L[l31][0]);
  const float cP = bf2f(S2L[l31][NR - 1]);

  // Q fragments for 32x32x16 (B operand), contiguous (pairs with contiguous K)
  bf16x8 qf[4];
  #pragma unroll
  for (int s = 0; s < 4; ++s)
    qf[s] = as_bf8(*(const u16x8*)(Qh + (size_t)qme * HD + 16 * s + 8 * hi));

  const int wk0 = wv_ * 256;           // this wave's kc range
  f32x16 oA = {}, oB = {};
  float ps = 0.f, ps0 = 0.f, bnd = 0.f;

  // ---- main loop: 8 tiles of 32 kc, NO barriers ----
  #pragma unroll
  for (int t = 0; t < 8; ++t) {
    const int kc0 = wk0 + 32 * t;
    bf16x8 kf[4];
    #pragma unroll
    for (int s = 0; s < 4; ++s)
      kf[s] = as_bf8(*(const u16x8*)(Kh + (size_t)(kc0 + l31) * HD + 16 * s + 8 * hi));

    f32x16 acc = {};
    #pragma unroll
    for (int s = 0; s < 4; ++s) acc = MFMA32(kf[s], qf[s], acc);

    // exp + rel bias. acc[r] = S[kc0 + kcoff][qme], kcoff=(r&3)+8*(r>>2)+4hi.
    float p[16];
    const bool isLow  = (kc0 <= q0 - 99);
    const bool isHigh = (kc0 >= q0 + 99);
    if (isLow | isHigh) {
      const float c = isLow ? cN : cP;
      #pragma unroll
      for (int r = 0; r < 16; ++r) p[r] = fexp2(fmaf(acc[r], KSCL, c));
      float s16 = ((p[0]+p[1])+(p[2]+p[3])) + ((p[4]+p[5])+(p[6]+p[7]))
                + ((p[8]+p[9])+(p[10]+p[11])) + ((p[12]+p[13])+(p[14]+p[15]));
      ps += s16;
      if (isLow) ps0 += s16;
    } else {
      #pragma unroll
      for (int r = 0; r < 16; ++r) {
        int kcoff = (r & 3) + 8 * (r >> 2) + 4 * hi;
        int dr = kc0 + kcoff - qme;
        int drc = dr < -MREL ? -MREL : (dr > MREL ? MREL : dr);
        float pe = fexp2(fmaf(acc[r], KSCL, bf2f(S2L[l31][drc + MREL])));
        p[r] = pe;
        ps += pe;
        if (dr <= -MREL) ps0 += pe;
        if (dr >= -67 && dr <= 67) { a2L[l31][dr + MREL] = f2bf(pe); bnd += pe; }
      }
    }

    // PV A-fragments: straight cvt_pk pack. Lane (q,hi)'s p-values already
    // sit at the split placement {4hi+0..3, 8+4hi+0..3} (+16 for paHi).
    bf16x8 paLo = frag4(cvtpk(p[0], p[1]),  cvtpk(p[2], p[3]),
                        cvtpk(p[4], p[5]),  cvtpk(p[6], p[7]));
    bf16x8 paHi = frag4(cvtpk(p[8], p[9]),  cvtpk(p[10], p[11]),
                        cvtpk(p[12], p[13]), cvtpk(p[14], p[15]));

    // V fragments (B operand) with MATCHING split placement
    const u16* vA = Vh + (size_t)l31 * Tt;
    const u16* vB = Vh + (size_t)(32 + l31) * Tt;
    bf16x8 vA0 = ldsplit(vA + kc0 + 4 * hi);
    bf16x8 vA1 = ldsplit(vA + kc0 + 16 + 4 * hi);
    bf16x8 vB0 = ldsplit(vB + kc0 + 4 * hi);
    bf16x8 vB1 = ldsplit(vB + kc0 + 16 + 4 * hi);
    oA = MFMA32(paLo, vA0, oA);
    oA = MFMA32(paHi, vA1, oA);
    oB = MFMA32(paLo, vB0, oB);
    oB = MFMA32(paHi, vB1, oB);
  }

  // ---- reductions across hi-halves then waves ----
  ps  += __shfl_xor(ps, 32);
  ps0 += __shfl_xor(ps0, 32);
  bnd += __shfl_xor(bnd, 32);
  if (l < 32) { red[0][wv_][l] = ps; red[1][wv_][l] = ps0; red[2][wv_][l] = bnd; }
  __syncthreads();

  if (tid < 32) {
    float t0 = red[0][0][tid] + red[0][1][tid] + red[0][2][tid] + red[0][3][tid];
    float t1 = red[1][0][tid] + red[1][1][tid] + red[1][2][tid] + red[1][3][tid];
    float tb = red[2][0][tid] + red[2][1][tid] + red[2][2][tid] + red[2][3][tid];
    a2L[tid][0]      = f2bf(t1);
    a2L[tid][NR - 1] = f2bf(t0 - t1 - tb);
    rowrcp[tid] = 1.0f / t0;
  }
  __syncthreads();

  // ---- a2 @ rel_v: 10 r-windows of 16 (both operands contiguous) ----
  for (int W = wv_; W < 10; W += 4) {
    bf16x8 aa = as_bf8(*(const u16x8*)&a2L[l31][W * 16 + 8 * hi]);
    bf16x8 rA = as_bf8(*(const u16x8*)(rvT + (size_t)l31 * NRP        + W * 16 + 8 * hi));
    bf16x8 rB = as_bf8(*(const u16x8*)(rvT + (size_t)(32 + l31) * NRP + W * 16 + 8 * hi));
    oA = MFMA32(aa, rA, oA);
    oB = MFMA32(aa, rB, oB);
  }

  // ---- accumulate O across waves ----
  #pragma unroll
  for (int r = 0; r < 16; ++r) {
    int qoff = (r & 3) + 8 * (r >> 2) + 4 * hi;
    atomicAdd(&Obuf[qoff][l31], oA[r]);
    atomicAdd(&Obuf[qoff][32 + l31], oB[r]);
  }
  __syncthreads();

  // ---- epilogue: normalize + store ----
  {
    int rq = tid >> 3, d8 = (tid & 7) * 8;
    float rc = rowrcp[rq];
    u16x8 o;
    #pragma unroll
    for (int j = 0; j < 8; ++j) o[j] = f2bf(Obuf[rq][d8 + j] * rc);
    *(u16x8*)&AO[((size_t)(bidx * Tt + q0 + rq)) * Cc + h * HD + d8] = o;
  }
}

// ---------------------------------------------------------------------------
// Kernel 3: output projection (unchanged).
// ---------------------------------------------------------------------------
__global__ __launch_bounds__(256) void out_gemm(
    const u16* __restrict__ AO, const u16* __restrict__ WoT,
    const float* __restrict__ bo, float* __restrict__ out)
{
  __shared__ u16 As[64][40];
  __shared__ u16 WTs[64][40];
  const int tid = threadIdx.x;
  const int wv_ = tid >> 6, l = tid & 63, lr = l & 15, lg = l >> 4;
  const int m0 = blockIdx.x * 64, n0 = blockIdx.y * 64;
  const int srow = tid >> 2, scol = (tid & 3) * 8;

  f32x4 acc[4];
  #pragma unroll
  for (int b = 0; b < 4; ++b) acc[b] = (f32x4){0.f, 0.f, 0.f, 0.f};

  for (int k0 = 0; k0 < Cc; k0 += 32) {
    u16x8 av = *(const u16x8*)(AO + (size_t)(m0 + srow) * Cc + k0 + scol);
    *(u16x8*)&As[srow][scol] = av;
    u16x8 wv2 = *(const u16x8*)(WoT + (size_t)(n0 + srow) * Cc + k0 + scol);
    *(u16x8*)&WTs[srow][scol] = wv2;
    __syncthreads();

    bf16x8 a = as_bf8(*(const u16x8*)&As[wv_ * 16 + lr][lg * 8]);
    #pragma unroll
    for (int nt = 0; nt < 4; ++nt) {
      bf16x8 b = as_bf8(*(const u16x8*)&WTs[nt * 16 + lr][lg * 8]);
      acc[nt] = MFMA16(a, b, acc[nt]);
    }
    __syncthreads();
  }

  #pragma unroll
  for (int nt = 0; nt < 4; ++nt) {
    int n = n0 + nt * 16 + lr;
    float bias = bo[n];
    #pragma unroll
    for (int i = 0; i < 4; ++i) {
      int m = m0 + wv_ * 16 + lg * 4 + i;
      out[(size_t)m * Cc + n] = acc[nt][i] + bias;
    }
  }
}

// ---------------------------------------------------------------------------
extern "C" void kernel_launch(void* const* d_in, const int* in_sizes, int n_in,
                              void* d_out, int out_size, void* d_ws, size_t ws_size,
                              hipStream_t stream) {
  const float* x  = (const float*)d_in[0];
  const float* Wq = (const float*)d_in[1];
  const float* bq = (const float*)d_in[2];
  const float* Wk = (const float*)d_in[3];
  const float* bk = (const float*)d_in[4];
  const float* Wv = (const float*)d_in[5];
  const float* bv = (const float*)d_in[6];
  const float* Wo = (const float*)d_in[7];
  const float* bo = (const float*)d_in[8];
  const float* rk = (const float*)d_in[9];
  const float* rv = (const float*)d_in[10];

  const size_t BHTD = (size_t)Bb * Hh * Tt * HD;   // 4,194,304 elements
  const size_t WSZ  = (size_t)Cc * Cc;             // 262,144

  u16* Qb = (u16*)d_out;
  u16* Kb = Qb + BHTD;
  u16* VT  = (u16*)d_ws;
  u16* AO  = VT + BHTD;
  u16* rvT = AO + BHTD;
  u16* WqT = rvT + (size_t)HD * NRP;
  u16* WkT = WqT + WSZ;
  u16* WvT = WkT + WSZ;
  u16* WoT = WvT + WSZ;
  float* outf = (float*)d_out;

  relv_prep<<<dim3((HD * NRP + 255) / 256), 256, 0, stream>>>(rv, rvT);
  w_prep<<<dim3(256, 4), 256, 0, stream>>>(Wq, Wk, Wv, Wo, WqT, WkT, WvT, WoT);
  qkv_gemm<<<dim3(128, 8), 256, 0, stream>>>(x, WqT, WkT, WvT, bq, bk, bv, Qb, Kb, VT);
  // bh fast (XCD locality); 32 q-rows per block
  attn_kernel<<<dim3(64, 32), 256, 0, stream>>>(Qb, Kb, VT, rvT, rk, AO);
  out_gemm<<<dim3(128, 8), 256, 0, stream>>>(AO, WoT, bo, outf);
}

// Round 15
// 239.006 us; speedup vs baseline: 1.0439x; 1.0439x over previous
//
#include <hip/hip_runtime.h>
#include <stdint.h>

#define Bb 8
#define Tt 1024
#define Cc 512
#define Hh 8
#define HD 64
#define MREL 68
#define NR 137           // 2*MREL+1
#define NRP 160          // k-extent padded for MFMA windows
#define SCALE 0.044194173824159216f     // 1/sqrt(512)  (ref scales by embed dim!)
#define KSCL  0.063763016845703125f     // SCALE * log2(e)

typedef unsigned short u16;
typedef unsigned int u32;
using u16x4  = __attribute__((ext_vector_type(4))) u16;
using u16x8  = __attribute__((ext_vector_type(8))) u16;
using u32x4  = __attribute__((ext_vector_type(4))) u32;
using f32x4  = __attribute__((ext_vector_type(4))) float;
using f32x16 = __attribute__((ext_vector_type(16))) float;
using bf16x8 = __attribute__((ext_vector_type(8))) __bf16;

__device__ __forceinline__ u16 f2bf(float f) {
  u32 u = __builtin_bit_cast(u32, f);
  u += 0x7FFF + ((u >> 16) & 1);       // RTNE
  return (u16)(u >> 16);
}
__device__ __forceinline__ float bf2f(u16 v) {
  return __builtin_bit_cast(float, (u32)v << 16);
}
__device__ __forceinline__ bf16x8 as_bf8(u16x8 v) { return __builtin_bit_cast(bf16x8, v); }
__device__ __forceinline__ bf16x8 frag4(u32 w0, u32 w1, u32 w2, u32 w3) {
  u32x4 v = {w0, w1, w2, w3};
  return __builtin_bit_cast(bf16x8, v);
}
__device__ __forceinline__ float fexp2(float x) {
  float r; asm("v_exp_f32 %0, %1" : "=v"(r) : "v"(x)); return r;
}
__device__ __forceinline__ u32 cvtpk(float lo, float hi) {
  u32 r; asm("v_cvt_pk_bf16_f32 %0, %1, %2" : "=v"(r) : "v"(lo), "v"(hi)); return r;
}

#define MFMA16(a, b, c) __builtin_amdgcn_mfma_f32_16x16x32_bf16((a), (b), (c), 0, 0, 0)
#define MFMA32(a, b, c) __builtin_amdgcn_mfma_f32_32x32x16_bf16((a), (b), (c), 0, 0, 0)

// Split-placement permutation (involution): within each 16-block of kc,
// swap sub-blocks [4,8) <-> [8,12). Baked into VT at the producer so the
// attn V-load is a contiguous u16x8 whose word->k placement matches the
// QK^T C/D interleave (r&3)+8*(r>>2)+4*hi. Verified: word j of a load at
// (kc0+16w+8hi) yields logical k = {4hi+j | j<4 ; 8+4hi+(j-4) | j>=4}.
__device__ __forceinline__ int vperm(int t) {
  int c = t & 15;
  int cp = (c & 4) ? ((c & 8) ? c : c + 4) : ((c & 8) ? c - 4 : c);
  return (t & ~15) | cp;
}

// ---------------------------------------------------------------------------
// Kernel 0a: transpose rel_v to bf16 [d][r] with zero pad.
// ---------------------------------------------------------------------------
__global__ __launch_bounds__(256) void relv_prep(
    const float* __restrict__ rel_v, u16* __restrict__ rvT)
{
  int i = blockIdx.x * 256 + threadIdx.x;
  if (i < HD * NRP) {
    int d = i / NRP, r = i - d * NRP;
    rvT[i] = (r < NR) ? f2bf(rel_v[r * HD + d]) : (u16)0;
  }
}

// ---------------------------------------------------------------------------
// Kernel 0b: convert the four 512x512 weights to bf16, TRANSPOSED [n][k].
// ---------------------------------------------------------------------------
__global__ __launch_bounds__(256) void w_prep(
    const float* __restrict__ Wq, const float* __restrict__ Wk,
    const float* __restrict__ Wv, const float* __restrict__ Wo,
    u16* __restrict__ WqT, u16* __restrict__ WkT,
    u16* __restrict__ WvT, u16* __restrict__ WoT)
{
  const float* W = blockIdx.y == 0 ? Wq : blockIdx.y == 1 ? Wk
                  : blockIdx.y == 2 ? Wv : Wo;
  u16* WT = blockIdx.y == 0 ? WqT : blockIdx.y == 1 ? WkT
           : blockIdx.y == 2 ? WvT : WoT;
  int i = blockIdx.x * 256 + threadIdx.x;   // over 512*128
  int n = i >> 7, k4 = (i & 127) * 4;
  u16x4 o;
  #pragma unroll
  for (int j = 0; j < 4; ++j) o[j] = f2bf(W[(size_t)(k4 + j) * Cc + n]);
  *(u16x4*)&WT[(size_t)n * Cc + k4] = o;
}

// ---------------------------------------------------------------------------
// Kernel 1: fused QKV projection. Q,K bf16 (B,H,T,HD); V TRANSPOSED bf16
// (B,H,HD,T) with kc split-permuted within 16-blocks (matches attn reader).
// ---------------------------------------------------------------------------
__global__ __launch_bounds__(256) void qkv_gemm(
    const float* __restrict__ x,
    const u16* __restrict__ WqT, const u16* __restrict__ WkT,
    const u16* __restrict__ WvT,
    const float* __restrict__ bq, const float* __restrict__ bk,
    const float* __restrict__ bv,
    u16* __restrict__ Qb, u16* __restrict__ Kb, u16* __restrict__ VTb)
{
  __shared__ u16 Xs[64][40];
  __shared__ u16 WTs[3][64][40];

  const u16* Wp[3] = {WqT, WkT, WvT};
  const float* bp[3] = {bq, bk, bv};

  const int tid = threadIdx.x;
  const int wv_ = tid >> 6;
  const int l   = tid & 63;
  const int lr  = l & 15, lg = l >> 4;
  const int m0  = blockIdx.x * 64;
  const int n0  = blockIdx.y * 64;
  const int srow = tid >> 2, scol = (tid & 3) * 8;

  f32x4 acc[3][4];
  #pragma unroll
  for (int a = 0; a < 3; ++a)
    #pragma unroll
    for (int b = 0; b < 4; ++b) acc[a][b] = (f32x4){0.f, 0.f, 0.f, 0.f};

  for (int k0 = 0; k0 < Cc; k0 += 32) {
    {
      const float* xp = x + (size_t)(m0 + srow) * Cc + k0 + scol;
      f32x4 v0 = *(const f32x4*)xp;
      f32x4 v1 = *(const f32x4*)(xp + 4);
      u16x8 o = {f2bf(v0[0]), f2bf(v0[1]), f2bf(v0[2]), f2bf(v0[3]),
                 f2bf(v1[0]), f2bf(v1[1]), f2bf(v1[2]), f2bf(v1[3])};
      *(u16x8*)&Xs[srow][scol] = o;
    }
    #pragma unroll
    for (int q3 = 0; q3 < 3; ++q3) {
      u16x8 w = *(const u16x8*)(Wp[q3] + (size_t)(n0 + srow) * Cc + k0 + scol);
      *(u16x8*)&WTs[q3][srow][scol] = w;
    }
    __syncthreads();

    bf16x8 a = as_bf8(*(const u16x8*)&Xs[wv_ * 16 + lr][lg * 8]);
    #pragma unroll
    for (int q3 = 0; q3 < 3; ++q3) {
      #pragma unroll
      for (int nt = 0; nt < 4; ++nt) {
        bf16x8 b = as_bf8(*(const u16x8*)&WTs[q3][nt * 16 + lr][lg * 8]);
        acc[q3][nt] = MFMA16(a, b, acc[q3][nt]);
      }
    }
    __syncthreads();
  }

  const int bidx = m0 >> 10;
  #pragma unroll
  for (int q3 = 0; q3 < 3; ++q3) {
    #pragma unroll
    for (int nt = 0; nt < 4; ++nt) {
      int n = n0 + nt * 16 + lr;
      int h = n >> 6, d = n & 63;
      float bias = bp[q3][n];
      #pragma unroll
      for (int i = 0; i < 4; ++i) {
        int m = m0 + wv_ * 16 + lg * 4 + i;
        int t = m & (Tt - 1);
        u16 o = f2bf(acc[q3][nt][i] + bias);
        size_t bh = (size_t)(bidx * Hh + h);
        if (q3 == 0)      Qb[(bh * Tt + t) * HD + d] = o;
        else if (q3 == 1) Kb[(bh * Tt + t) * HD + d] = o;
        else              VTb[(bh * HD + d) * Tt + vperm(t)] = o;
      }
    }
  }
}

// ---------------------------------------------------------------------------
// Kernel 2: relative attention. Block = (b,h) x 32 q-rows; wave owns a
// 256-wide kc quarter. Swapped 32x32x16 QK^T -> lane holds P[q=lane&31][16kc]
// in registers; PV A-fragments via cvt_pk only; V pre-permuted in global so
// its contiguous load placement matches P's. Depth-1 K prefetch; V loads
// issued a full QK^T+exp chain ahead of use. No barriers in the k-loop.
// ---------------------------------------------------------------------------
__global__ __launch_bounds__(256, 3) void attn_kernel(
    const u16* __restrict__ Qb, const u16* __restrict__ Kb,
    const u16* __restrict__ VTb, const u16* __restrict__ rvT,
    const float* __restrict__ rel_k,
    u16* __restrict__ AO)
{
  __shared__ u16 S2L[32][144];     // (Q @ rel_k^T) * KSCL
  __shared__ u16 a2L[32][176];     // aggregated P over rel index (16B rows)
  __shared__ float Obuf[32][64];   // O accumulator across waves
  __shared__ float red[3][4][32];  // rowsum / s0 / band partials per wave
  __shared__ float rowrcp[32];

  const int tid = threadIdx.x;
  const int wv_ = tid >> 6, l = tid & 63;
  const int l31 = l & 31, hi = l >> 5;
  const int lr16 = l & 15, lg16 = l >> 4;
  const int bh = blockIdx.x;           // FAST dim -> XCD = bh % 8
  const int q0 = blockIdx.y * 32;
  const int bidx = bh >> 3, h = bh & 7;

  const u16* Qh = Qb  + (size_t)bh * Tt * HD;
  const u16* Kh = Kb  + (size_t)bh * Tt * HD;
  const u16* Vh = VTb + (size_t)bh * HD * Tt;

  const int wk0 = wv_ * 256;           // this wave's kc range

  // K tile-0 preload (latency hides under the S2 phase)
  const u16* kfp = Kh + (size_t)(wk0 + l31) * HD + 8 * hi;
  bf16x8 kf[4], kn[4];
  #pragma unroll
  for (int s = 0; s < 4; ++s)
    kf[s] = as_bf8(*(const u16x8*)(kfp + 16 * s));

  // zero a2L + Obuf
  for (int i = tid; i < 32 * 176 / 2; i += 256) ((u32*)a2L)[i] = 0;
  for (int i = tid; i < 32 * 64; i += 256) ((float*)Obuf)[i] = 0.f;

  // ---- S2 = (Q @ rel_k^T) * KSCL  (16x16 MFMA, two q-halves) ----
  #pragma unroll
  for (int h16 = 0; h16 < 2; ++h16) {
    bf16x8 aQ0 = as_bf8(*(const u16x8*)(Qh + (size_t)(q0 + h16 * 16 + lr16) * HD + lg16 * 8));
    bf16x8 aQ1 = as_bf8(*(const u16x8*)(Qh + (size_t)(q0 + h16 * 16 + lr16) * HD + 32 + lg16 * 8));
    for (int ct = wv_; ct < 9; ct += 4) {
      int r = ct * 16 + lr16;
      f32x4 acc = {0.f, 0.f, 0.f, 0.f};
      #pragma unroll
      for (int d0 = 0; d0 < 64; d0 += 32) {
        u16x8 bbits = {0, 0, 0, 0, 0, 0, 0, 0};
        if (r < NR) {
          f32x4 v0 = *(const f32x4*)(rel_k + (size_t)r * HD + d0 + lg16 * 8);
          f32x4 v1 = *(const f32x4*)(rel_k + (size_t)r * HD + d0 + lg16 * 8 + 4);
          bbits = (u16x8){f2bf(v0[0]), f2bf(v0[1]), f2bf(v0[2]), f2bf(v0[3]),
                          f2bf(v1[0]), f2bf(v1[1]), f2bf(v1[2]), f2bf(v1[3])};
        }
        acc = MFMA16(d0 ? aQ1 : aQ0, as_bf8(bbits), acc);
      }
      #pragma unroll
      for (int i = 0; i < 4; ++i)
        S2L[h16 * 16 + lg16 * 4 + i][ct * 16 + lr16] = f2bf(acc[i] * KSCL);
    }
  }
  __syncthreads();

  // ---- per-lane setup (q = q0 + l31 is FIXED) ----
  const int qme = q0 + l31;
  const float cN = bf2f(S2L[l31][0]);
  const float cP = bf2f(S2L[l31][NR - 1]);

  // Q fragments for 32x32x16 (B operand), contiguous (pairs with contiguous K)
  bf16x8 qf[4];
  #pragma unroll
  for (int s = 0; s < 4; ++s)
    qf[s] = as_bf8(*(const u16x8*)(Qh + (size_t)qme * HD + 16 * s + 8 * hi));

  const u16* vAp = Vh + (size_t)l31 * Tt + 8 * hi;         // d = l31
  const u16* vBp = Vh + (size_t)(32 + l31) * Tt + 8 * hi;  // d = 32+l31

  f32x16 oA = {}, oB = {};
  float ps = 0.f, ps0 = 0.f, bnd = 0.f;

  // ---- main loop: 8 tiles of 32 kc, NO barriers, depth-1 pipeline ----
  #pragma unroll
  for (int t = 0; t < 8; ++t) {
    const int kc0 = wk0 + 32 * t;

    // V loads for THIS tile (consumed after QK^T + exp chain)
    bf16x8 vA0 = as_bf8(*(const u16x8*)(vAp + kc0));
    bf16x8 vA1 = as_bf8(*(const u16x8*)(vAp + kc0 + 16));
    bf16x8 vB0 = as_bf8(*(const u16x8*)(vBp + kc0));
    bf16x8 vB1 = as_bf8(*(const u16x8*)(vBp + kc0 + 16));
    // K prefetch for NEXT tile
    if (t < 7) {
      #pragma unroll
      for (int s = 0; s < 4; ++s)
        kn[s] = as_bf8(*(const u16x8*)(kfp + (size_t)(t + 1) * 32 * HD + 16 * s));
    }

    f32x16 acc = {};
    #pragma unroll
    for (int s = 0; s < 4; ++s) acc = MFMA32(kf[s], qf[s], acc);

    // exp + rel bias. acc[r] = S[kc0 + kcoff][qme], kcoff=(r&3)+8*(r>>2)+4hi.
    float p[16];
    const bool isLow  = (kc0 <= q0 - 99);
    const bool isHigh = (kc0 >= q0 + 99);
    if (isLow | isHigh) {
      const float c = isLow ? cN : cP;
      #pragma unroll
      for (int r = 0; r < 16; ++r) p[r] = fexp2(fmaf(acc[r], KSCL, c));
      float s16 = ((p[0]+p[1])+(p[2]+p[3])) + ((p[4]+p[5])+(p[6]+p[7]))
                + ((p[8]+p[9])+(p[10]+p[11])) + ((p[12]+p[13])+(p[14]+p[15]));
      ps += s16;
      if (isLow) ps0 += s16;
    } else {
      #pragma unroll
      for (int r = 0; r < 16; ++r) {
        int kcoff = (r & 3) + 8 * (r >> 2) + 4 * hi;
        int dr = kc0 + kcoff - qme;
        int drc = dr < -MREL ? -MREL : (dr > MREL ? MREL : dr);
        float pe = fexp2(fmaf(acc[r], KSCL, bf2f(S2L[l31][drc + MREL])));
        p[r] = pe;
        ps += pe;
        if (dr <= -MREL) ps0 += pe;
        if (dr >= -67 && dr <= 67) { a2L[l31][dr + MREL] = f2bf(pe); bnd += pe; }
      }
    }

    // PV A-fragments: straight cvt_pk pack (placement matches permuted V)
    bf16x8 paLo = frag4(cvtpk(p[0], p[1]),  cvtpk(p[2], p[3]),
                        cvtpk(p[4], p[5]),  cvtpk(p[6], p[7]));
    bf16x8 paHi = frag4(cvtpk(p[8], p[9]),  cvtpk(p[10], p[11]),
                        cvtpk(p[12], p[13]), cvtpk(p[14], p[15]));

    oA = MFMA32(paLo, vA0, oA);
    oA = MFMA32(paHi, vA1, oA);
    oB = MFMA32(paLo, vB0, oB);
    oB = MFMA32(paHi, vB1, oB);

    #pragma unroll
    for (int s = 0; s < 4; ++s) kf[s] = kn[s];
  }

  // ---- reductions across hi-halves then waves ----
  ps  += __shfl_xor(ps, 32);
  ps0 += __shfl_xor(ps0, 32);
  bnd += __shfl_xor(bnd, 32);
  if (l < 32) { red[0][wv_][l] = ps; red[1][wv_][l] = ps0; red[2][wv_][l] = bnd; }
  __syncthreads();

  if (tid < 32) {
    float t0 = red[0][0][tid] + red[0][1][tid] + red[0][2][tid] + red[0][3][tid];
    float t1 = red[1][0][tid] + red[1][1][tid] + red[1][2][tid] + red[1][3][tid];
    float tb = red[2][0][tid] + red[2][1][tid] + red[2][2][tid] + red[2][3][tid];
    a2L[tid][0]      = f2bf(t1);
    a2L[tid][NR - 1] = f2bf(t0 - t1 - tb);
    rowrcp[tid] = 1.0f / t0;
  }
  __syncthreads();

  // ---- a2 @ rel_v: 10 r-windows of 16 (both operands contiguous) ----
  for (int W = wv_; W < 10; W += 4) {
    bf16x8 aa = as_bf8(*(const u16x8*)&a2L[l31][W * 16 + 8 * hi]);
    bf16x8 rA = as_bf8(*(const u16x8*)(rvT + (size_t)l31 * NRP        + W * 16 + 8 * hi));
    bf16x8 rB = as_bf8(*(const u16x8*)(rvT + (size_t)(32 + l31) * NRP + W * 16 + 8 * hi));
    oA = MFMA32(aa, rA, oA);
    oB = MFMA32(aa, rB, oB);
  }

  // ---- accumulate O across waves ----
  #pragma unroll
  for (int r = 0; r < 16; ++r) {
    int qoff = (r & 3) + 8 * (r >> 2) + 4 * hi;
    atomicAdd(&Obuf[qoff][l31], oA[r]);
    atomicAdd(&Obuf[qoff][32 + l31], oB[r]);
  }
  __syncthreads();

  // ---- epilogue: normalize + store ----
  {
    int rq = tid >> 3, d8 = (tid & 7) * 8;
    float rc = rowrcp[rq];
    u16x8 o;
    #pragma unroll
    for (int j = 0; j < 8; ++j) o[j] = f2bf(Obuf[rq][d8 + j] * rc);
    *(u16x8*)&AO[((size_t)(bidx * Tt + q0 + rq)) * Cc + h * HD + d8] = o;
  }
}

// ---------------------------------------------------------------------------
// Kernel 3: output projection (unchanged).
// ---------------------------------------------------------------------------
__global__ __launch_bounds__(256) void out_gemm(
    const u16* __restrict__ AO, const u16* __restrict__ WoT,
    const float* __restrict__ bo, float* __restrict__ out)
{
  __shared__ u16 As[64][40];
  __shared__ u16 WTs[64][40];
  const int tid = threadIdx.x;
  const int wv_ = tid >> 6, l = tid & 63, lr = l & 15, lg = l >> 4;
  const int m0 = blockIdx.x * 64, n0 = blockIdx.y * 64;
  const int srow = tid >> 2, scol = (tid & 3) * 8;

  f32x4 acc[4];
  #pragma unroll
  for (int b = 0; b < 4; ++b) acc[b] = (f32x4){0.f, 0.f, 0.f, 0.f};

  for (int k0 = 0; k0 < Cc; k0 += 32) {
    u16x8 av = *(const u16x8*)(AO + (size_t)(m0 + srow) * Cc + k0 + scol);
    *(u16x8*)&As[srow][scol] = av;
    u16x8 wv2 = *(const u16x8*)(WoT + (size_t)(n0 + srow) * Cc + k0 + scol);
    *(u16x8*)&WTs[srow][scol] = wv2;
    __syncthreads();

    bf16x8 a = as_bf8(*(const u16x8*)&As[wv_ * 16 + lr][lg * 8]);
    #pragma unroll
    for (int nt = 0; nt < 4; ++nt) {
      bf16x8 b = as_bf8(*(const u16x8*)&WTs[nt * 16 + lr][lg * 8]);
      acc[nt] = MFMA16(a, b, acc[nt]);
    }
    __syncthreads();
  }

  #pragma unroll
  for (int nt = 0; nt < 4; ++nt) {
    int n = n0 + nt * 16 + lr;
    float bias = bo[n];
    #pragma unroll
    for (int i = 0; i < 4; ++i) {
      int m = m0 + wv_ * 16 + lg * 4 + i;
      out[(size_t)m * Cc + n] = acc[nt][i] + bias;
    }
  }
}

// ---------------------------------------------------------------------------
extern "C" void kernel_launch(void* const* d_in, const int* in_sizes, int n_in,
                              void* d_out, int out_size, void* d_ws, size_t ws_size,
                              hipStream_t stream) {
  const float* x  = (const float*)d_in[0];
  const float* Wq = (const float*)d_in[1];
  const float* bq = (const float*)d_in[2];
  const float* Wk = (const float*)d_in[3];
  const float* bk = (const float*)d_in[4];
  const float* Wv = (const float*)d_in[5];
  const float* bv = (const float*)d_in[6];
  const float* Wo = (const float*)d_in[7];
  const float* bo = (const float*)d_in[8];
  const float* rk = (const float*)d_in[9];
  const float* rv = (const float*)d_in[10];

  const size_t BHTD = (size_t)Bb * Hh * Tt * HD;   // 4,194,304 elements
  const size_t WSZ  = (size_t)Cc * Cc;             // 262,144

  u16* Qb = (u16*)d_out;
  u16* Kb = Qb + BHTD;
  u16* VT  = (u16*)d_ws;
  u16* AO  = VT + BHTD;
  u16* rvT = AO + BHTD;
  u16* WqT = rvT + (size_t)HD * NRP;
  u16* WkT = WqT + WSZ;
  u16* WvT = WkT + WSZ;
  u16* WoT = WvT + WSZ;
  float* outf = (float*)d_out;

  relv_prep<<<dim3((HD * NRP + 255) / 256), 256, 0, stream>>>(rv, rvT);
  w_prep<<<dim3(256, 4), 256, 0, stream>>>(Wq, Wk, Wv, Wo, WqT, WkT, WvT, WoT);
  qkv_gemm<<<dim3(128, 8), 256, 0, stream>>>(x, WqT, WkT, WvT, bq, bk, bv, Qb, Kb, VT);
  // bh fast (XCD locality); 32 q-rows per block
  attn_kernel<<<dim3(64, 32), 256, 0, stream>>>(Qb, Kb, VT, rvT, rk, AO);
  out_gemm<<<dim3(128, 8), 256, 0, stream>>>(AO, WoT, bo, outf);
}